// Round 13
// baseline (165.366 us; speedup 1.0000x reference)
//
#include <hip/hip_runtime.h>

#define NH 32
#define KVHN 8
#define HD 128
#define QL 1024
#define MS 4096
#define KVB 64

typedef __bf16 bf16x8 __attribute__((ext_vector_type(8)));
typedef __bf16 bf16x4 __attribute__((ext_vector_type(4)));
typedef float f32x4 __attribute__((ext_vector_type(4)));
typedef float f32x16 __attribute__((ext_vector_type(16)));
typedef unsigned int u32x4 __attribute__((ext_vector_type(4)));

// ws: Kbf [8][4096][128] bf16, rows pre-swizzled (chunk16 ^= pos&7)      (8 MB)
//     Vt  [8][64 tiles][128 d][64 kv] bf16, pre-swizzled (chunk ^= d&7)  (8 MB)

__device__ __forceinline__ void gload16(const void* g, void* l) {
    __builtin_amdgcn_global_load_lds(
        (const __attribute__((address_space(1))) unsigned int*)g,
        (__attribute__((address_space(3))) unsigned int*)l, 16, 0, 0);
}

__device__ __forceinline__ unsigned int pk2(float a, float b) {
    union { __bf16 h; unsigned short u; } x, y;
    x.h = (__bf16)a; y.h = (__bf16)b;
    return (unsigned int)x.u | ((unsigned int)y.u << 16);
}

__device__ __forceinline__ float exp2fast(float x) {
    return __builtin_amdgcn_exp2f(x);   // v_exp_f32: D = 2^S0
}

__device__ __forceinline__ u32x4 nt_load(const u32x4* p) {
    return __builtin_nontemporal_load(p);
}
__device__ __forceinline__ void nt_store(u32x4* p, u32x4 v) {
    __builtin_nontemporal_store(v, p);
}

// ---------------- Kernel A: bf16 K pack + swizzled V^T pack (bp row only) ----------
__global__ __launch_bounds__(256) void pack_kernel(
    const float4* __restrict__ kn, const float4* __restrict__ vn,
    const float4* __restrict__ pk, const float4* __restrict__ pv,
    const int* __restrict__ bp_p, const int* __restrict__ sp_p,
    __bf16* __restrict__ kbf, __bf16* __restrict__ vt)
{
    __shared__ float vtile[8][132];               // padded: column reads conflict-free
    int li = blockIdx.x * 256 + threadIdx.x;     // within-batch float4 index (2^20 total)
    int bp = *bp_p, sp = *sp_p;
    int d4  = li & 31;
    int pos = (li >> 5) & 4095;
    int kvh = li >> 17;
    float4 kv4, vv4;
    if (pos >= sp && pos < sp + QL) {
        int ns = (kvh * QL + (pos - sp)) * 32 + d4;
        kv4 = kn[ns]; vv4 = vn[ns];
    } else {
        int gi = (bp << 20) + li;
        kv4 = pk[gi]; vv4 = pv[gi];
    }
    {
        bf16x4 o;
        o[0] = (__bf16)kv4.x; o[1] = (__bf16)kv4.y;
        o[2] = (__bf16)kv4.z; o[3] = (__bf16)kv4.w;
        int c16 = d4 >> 1, half = d4 & 1;
        *(bf16x4*)(kbf + ((size_t)kvh * MS + pos) * HD
                       + ((c16 ^ (pos & 7)) * 8 + half * 4)) = o;
        *(float4*)&vtile[threadIdx.x >> 5][d4 * 4] = vv4;
    }
    __syncthreads();
    if (threadIdx.x < 128) {
        int d  = threadIdx.x;
        int p0 = (blockIdx.x * 8) & 4095;        // block's first pos (multiple of 8)
        int pt = p0 >> 6, chk = (p0 & 63) >> 3;
        bf16x8 o;
        #pragma unroll
        for (int j = 0; j < 8; ++j) o[j] = (__bf16)vtile[j][d];
        *(bf16x8*)(vt + (((size_t)kvh * 64 + pt) * HD + d) * 64
                      + ((chk ^ (d & 7)) * 8)) = o;
    }
}

// ---------------- Mega kernel: wave-level role split -------------------------------
// 512 blocks x 512 threads. Waves 0-3: R7 attn core (dbuf LDS). Waves 4-7: cache
// copy (nontemporal), matched __syncthreads counts (1 + n_super + 2). Every CU gets
// 2 blocks = 8 attn waves (full attn occupancy) + 8 copy waves streaming HBM.
__global__ __launch_bounds__(512, 4) void mega_kernel(
    const float* __restrict__ q,
    const int* __restrict__ bp_p, const int* __restrict__ sp_p,
    const float* __restrict__ scale_p,
    const __bf16* __restrict__ kbf, const __bf16* __restrict__ vt,
    const float4* __restrict__ knf, const float4* __restrict__ vnf,
    const float4* __restrict__ pkf, const float4* __restrict__ pvf,
    float4* __restrict__ okf, float4* __restrict__ ovf,
    float* __restrict__ out)
{
    __shared__ __align__(16) unsigned char smem[65536];   // 2 x {K 16K | V 16K}

    const int bid = blockIdx.x;
    const int tid = threadIdx.x;
    const int sp  = *sp_p;
    const int bp  = *bp_p;

    // XCD-aware decode: bid%8 == kvh so each XCD owns one kv-head (4MB = L2)
    int kvh = bid & 7;
    int inner = (bid & 255) >> 3;       // 0..31
    int headLocal = inner & 3;
    int j = inner >> 2;                 // 0..7
    int qtile = (bid < 256) ? j : 15 - j;   // bid and bid+256 pair long+short
    int head = kvh * 4 + headLocal;
    const int q0 = qtile * 64;
    const int n_super = (sp + q0 + 64) >> 6;

    if (tid >= 256) {
        // ================= COPY ROLE (waves 4-7): 16384 float4 of one cache =======
        const int ctid = tid - 256;
        const u32x4* csrc_new  = (const u32x4*)((bid < 256) ? knf : vnf);
        const u32x4* csrc_past = (const u32x4*)((bid < 256) ? pkf : pvf);
        u32x4*       cdst      = (u32x4*)((bid < 256) ? okf : ovf);
        const int    cbase     = (bid & 255) * 16384;

        __syncthreads();                               // match attn's initial barrier
        for (int it = 0; it < n_super; ++it) {
            if (it < 16) {
                u32x4 t[4];
                #pragma unroll
                for (int jj = 0; jj < 4; ++jj) {
                    int idx = cbase + it * 1024 + jj * 256 + ctid;
                    int d4  = idx & 31;
                    int pos = (idx >> 5) & 4095;
                    int ck  = (idx >> 17) & 7;
                    int b   = idx >> 20;
                    t[jj] = (b == bp && pos >= sp && pos < sp + QL)
                        ? nt_load(&csrc_new[(ck * QL + (pos - sp)) * 32 + d4])
                        : nt_load(&csrc_past[idx]);
                }
                #pragma unroll
                for (int jj = 0; jj < 4; ++jj)
                    nt_store(&cdst[cbase + it * 1024 + jj * 256 + ctid], t[jj]);
            }
            __syncthreads();                           // match attn's loop barrier
        }
        // defensive tail if n_super < 16 (not hit at sp=1024)
        for (int s = n_super; s < 16; ++s) {
            u32x4 t[4];
            #pragma unroll
            for (int jj = 0; jj < 4; ++jj) {
                int idx = cbase + s * 1024 + jj * 256 + ctid;
                int d4  = idx & 31;
                int pos = (idx >> 5) & 4095;
                int ck  = (idx >> 17) & 7;
                int b   = idx >> 20;
                t[jj] = (b == bp && pos >= sp && pos < sp + QL)
                    ? nt_load(&csrc_new[(ck * QL + (pos - sp)) * 32 + d4])
                    : nt_load(&csrc_past[idx]);
            }
            #pragma unroll
            for (int jj = 0; jj < 4; ++jj)
                nt_store(&cdst[cbase + s * 1024 + jj * 256 + ctid], t[jj]);
        }
        __syncthreads();                               // match attn epilogue barrier 1
        __syncthreads();                               // match attn epilogue barrier 2
        return;
    }

    // ==================== ATTN ROLE (waves 0-3; R7 core, double-buffered) =========
    const float scl = *scale_p * 1.44269504088896340736f;  // fold log2(e): exp2 domain

    const int wave   = tid >> 6;
    const int qsub   = wave & 1;        // which 32 q-rows
    const int kvhalf = wave >> 1;       // which 32-kv half of each super-tile
    const int lane   = tid & 63;
    const int hi     = lane >> 5;
    const int c31    = lane & 31;
    const int qb     = q0 + qsub * 32;
    const int myq    = qb + c31;

    const unsigned char* krow = (const unsigned char*)(kbf + (size_t)kvh * MS * HD);
    const unsigned char* vrow = (const unsigned char*)(vt + (size_t)kvh * 64 * HD * 64);

    // ---- Q B-fragments (hoisted, scale*log2e folded) ----
    bf16x8 qf[8];
    #pragma unroll
    for (int dc = 0; dc < 8; ++dc) {
        const float* src = q + ((size_t)(head * QL + qb + c31) * HD + dc * 16 + hi * 8);
        float4 f0 = *(const float4*)src;
        float4 f1 = *(const float4*)(src + 4);
        bf16x8 v;
        v[0]=(__bf16)(f0.x*scl); v[1]=(__bf16)(f0.y*scl);
        v[2]=(__bf16)(f0.z*scl); v[3]=(__bf16)(f0.w*scl);
        v[4]=(__bf16)(f1.x*scl); v[5]=(__bf16)(f1.y*scl);
        v[6]=(__bf16)(f1.z*scl); v[7]=(__bf16)(f1.w*scl);
        qf[dc] = v;
    }

    f32x16 acc[4];
    #pragma unroll
    for (int dsub = 0; dsub < 4; ++dsub)
        #pragma unroll
        for (int r = 0; r < 16; ++r) acc[dsub][r] = 0.f;
    float m_run = -1e30f, l_run = 0.f;

    auto stage = [&](int buf, int t) {
        const unsigned char* kt = krow + (size_t)t * 16384;
        const unsigned char* vtile = vrow + (size_t)t * 16384;
        unsigned char* kl = smem + buf * 32768;
        unsigned char* vl = kl + 16384;
        #pragma unroll
        for (int p = 0; p < 4; ++p) {
            int off = p * 4096 + tid * 16;
            gload16(kt + off, kl + off);
            gload16(vtile + off, vl + off);
        }
    };

    int cur = 0;
    stage(0, 0);
    __syncthreads();

    for (int it = 0; it < n_super; ++it) {
        const int n0 = it * KVB + kvhalf * 32;   // this wave's 32-kv window
        if (it + 1 < n_super) stage(cur ^ 1, it + 1);

        const unsigned char* Ksm = smem + cur * 32768;
        const unsigned char* Vsm = Ksm + 16384;

        // ---- QK^T (swapped): two independent 4-deep MFMA chains ----
        f32x16 st0, st1;
        #pragma unroll
        for (int r = 0; r < 16; ++r) { st0[r] = 0.f; st1[r] = 0.f; }
        int kr = kvhalf * 32 + c31;
        __builtin_amdgcn_s_setprio(1);
        #pragma unroll
        for (int dc = 0; dc < 4; ++dc) {
            bf16x8 ka = *(const bf16x8*)(Ksm + kr * 256 + (((2 * dc + hi) ^ (kr & 7)) << 4));
            st0 = __builtin_amdgcn_mfma_f32_32x32x16_bf16(ka, qf[dc], st0, 0, 0, 0);
            bf16x8 kb = *(const bf16x8*)(Ksm + kr * 256 + (((2 * (dc + 4) + hi) ^ (kr & 7)) << 4));
            st1 = __builtin_amdgcn_mfma_f32_32x32x16_bf16(kb, qf[dc + 4], st1, 0, 0, 0);
        }
        __builtin_amdgcn_s_setprio(0);
        f32x16 st = st0 + st1;

        // ---- mask + in-register row max (pairwise tree) ----
        const bool need_mask = (n0 + 31) > (sp + qb);
        if (need_mask) {
            #pragma unroll
            for (int r = 0; r < 16; ++r) {
                int kvg = n0 + (r & 3) + 8 * (r >> 2) + 4 * hi;
                if (kvg > sp + myq) st[r] = -1e30f;
            }
        }
        float m01 = fmaxf(fmaxf(st[0], st[1]), fmaxf(st[2], st[3]));
        float m23 = fmaxf(fmaxf(st[4], st[5]), fmaxf(st[6], st[7]));
        float m45 = fmaxf(fmaxf(st[8], st[9]), fmaxf(st[10], st[11]));
        float m67 = fmaxf(fmaxf(st[12], st[13]), fmaxf(st[14], st[15]));
        float mx = fmaxf(fmaxf(m01, m23), fmaxf(m45, m67));
        mx = fmaxf(mx, __shfl_xor(mx, 32));

        // ---- defer-max rescale (rare), exp2 domain ----
        if (!__all(mx <= m_run + 8.0f)) {
            float nm = fmaxf(m_run, mx);
            float corr = exp2fast(m_run - nm);
            m_run = nm;
            l_run *= corr;
            #pragma unroll
            for (int r = 0; r < 16; ++r) {
                int qsrc = (r & 3) + 8 * (r >> 2) + 4 * hi;
                float cq = __shfl(corr, qsrc);
                acc[0][r] *= cq; acc[1][r] *= cq; acc[2][r] *= cq; acc[3][r] *= cq;
            }
        }

        // ---- exp2 + tree sum (in-register) ----
        #pragma unroll
        for (int r = 0; r < 16; ++r) st[r] = exp2fast(st[r] - m_run);
        {
            float s0 = (st[0] + st[1]) + (st[2] + st[3]);
            float s1 = (st[4] + st[5]) + (st[6] + st[7]);
            float s2 = (st[8] + st[9]) + (st[10] + st[11]);
            float s3 = (st[12] + st[13]) + (st[14] + st[15]);
            l_run += (s0 + s1) + (s2 + s3);
        }

        // ---- pack P to bf16, permlane32_swap half-exchange, assemble PA frags ----
        unsigned int loW[4], hiW[4];
        #pragma unroll
        for (int qd = 0; qd < 2; ++qd) {
            int b = qd * 8;
            loW[qd*2+0] = pk2(st[b+0], st[b+1]);
            loW[qd*2+1] = pk2(st[b+2], st[b+3]);
            hiW[qd*2+0] = pk2(st[b+4], st[b+5]);
            hiW[qd*2+1] = pk2(st[b+6], st[b+7]);
        }
        bf16x8 pfrag[2];
        #pragma unroll
        for (int qd = 0; qd < 2; ++qd) {
            unsigned int a0 = loW[qd*2+0], b0 = hiW[qd*2+0];
            unsigned int a1 = loW[qd*2+1], b1 = hiW[qd*2+1];
            asm("v_permlane32_swap_b32 %0, %1" : "+v"(a0), "+v"(b0));
            asm("v_permlane32_swap_b32 %0, %1" : "+v"(a1), "+v"(b1));
            union { unsigned int u[4]; bf16x8 v; } fu;
            fu.u[0] = a0; fu.u[1] = a1; fu.u[2] = b0; fu.u[3] = b1;
            pfrag[qd] = fu.v;
        }

        // ---- PV: O(32q x 128d) += P(32x32) . V(32x128) on this kv half ----
        __builtin_amdgcn_s_setprio(1);
        #pragma unroll
        for (int dsub = 0; dsub < 4; ++dsub) {
            int vr = dsub * 32 + c31;
            #pragma unroll
            for (int qd = 0; qd < 2; ++qd) {
                int ksg = kvhalf * 2 + qd;
                bf16x8 vf = *(const bf16x8*)(Vsm + vr * 128 + (((ksg * 2 + hi) ^ (vr & 7)) << 4));
                acc[dsub] = __builtin_amdgcn_mfma_f32_32x32x16_bf16(pfrag[qd], vf, acc[dsub], 0, 0, 0);
            }
        }
        __builtin_amdgcn_s_setprio(0);

        __syncthreads();
        cur ^= 1;
    }

    // ---- epilogue: merge kv-half pairs via LDS, normalize, store ----
    float l_full = l_run + __shfl_xor(l_run, 32);
    float* mlm = (float*)smem;            // [4][32] running max
    float* mll = (float*)smem + 128;      // [4][32] denom
    if (hi == 0) { mlm[wave * 32 + c31] = m_run; mll[wave * 32 + c31] = l_full; }
    __syncthreads();
    int pw = wave ^ 2;
    float m_o = mlm[pw * 32 + c31];
    float l_o = mll[pw * 32 + c31];
    float m_n = fmaxf(m_run, m_o);
    float sc   = exp2fast(m_run - m_n);
    float sc_o = exp2fast(m_o - m_n);
    float linv = 1.0f / (l_full * sc + l_o * sc_o);
    float* Oex = (float*)(smem + 1024) + (size_t)qsub * 32 * 128;
    if (kvhalf) {
        #pragma unroll
        for (int r = 0; r < 16; ++r) {
            int qsrc = (r & 3) + 8 * (r >> 2) + 4 * hi;
            float s = __shfl(sc, qsrc);
            #pragma unroll
            for (int dsub = 0; dsub < 4; ++dsub)
                Oex[qsrc * 128 + dsub * 32 + c31] = acc[dsub][r] * s;
        }
    }
    __syncthreads();
    if (!kvhalf) {
        #pragma unroll
        for (int r = 0; r < 16; ++r) {
            int qsrc = (r & 3) + 8 * (r >> 2) + 4 * hi;
            float s  = __shfl(sc, qsrc);
            float lq = __shfl(linv, qsrc);
            float* orow = out + (size_t)(qb + qsrc) * (NH * HD) + head * HD;
            #pragma unroll
            for (int dsub = 0; dsub < 4; ++dsub)
                orow[dsub * 32 + c31] =
                    (acc[dsub][r] * s + Oex[qsrc * 128 + dsub * 32 + c31]) * lq;
        }
    }
}

// ---------------- launch ----------------
extern "C" void kernel_launch(void* const* d_in, const int* in_sizes, int n_in,
                              void* d_out, int out_size, void* d_ws, size_t ws_size,
                              hipStream_t stream)
{
    const float* q_st   = (const float*)d_in[0];
    const float* k_new  = (const float*)d_in[1];
    const float* v_new  = (const float*)d_in[2];
    const int*   bp_p   = (const int*)d_in[4];
    const float* past_k = (const float*)d_in[5];
    const float* past_v = (const float*)d_in[6];
    const int*   sp_p   = (const int*)d_in[7];
    const float* scl_p  = (const float*)d_in[8];

    float* out_attn = (float*)d_out;                       // [1024][4096]
    float* out_k    = out_attn + (size_t)QL * NH * HD;     // [4][8][4096][128]
    float* out_v    = out_k + (size_t)4 * KVHN * MS * HD;

    __bf16* kbf = (__bf16*)d_ws;                           // [8][4096][128] swizzled
    __bf16* vtw = kbf + (size_t)KVHN * MS * HD;            // [8][64][128][64] swizzled

    pack_kernel<<<4096, 256, 0, stream>>>(
        (const float4*)k_new, (const float4*)v_new,
        (const float4*)past_k, (const float4*)past_v,
        bp_p, sp_p, kbf, vtw);

    mega_kernel<<<512, 512, 0, stream>>>(
        q_st, bp_p, sp_p, scl_p, kbf, vtw,
        (const float4*)k_new, (const float4*)v_new,
        (const float4*)past_k, (const float4*)past_v,
        (float4*)out_k, (float4*)out_v, out_attn);
}

// Round 14
// 102.810 us; speedup vs baseline: 1.6085x; 1.6085x over previous
//
#include <hip/hip_runtime.h>

#define NH 32
#define KVHN 8
#define HD 128
#define QL 1024
#define MS 4096
#define KVB 64

typedef __bf16 bf16x8 __attribute__((ext_vector_type(8)));
typedef __bf16 bf16x4 __attribute__((ext_vector_type(4)));
typedef float f32x4 __attribute__((ext_vector_type(4)));
typedef float f32x16 __attribute__((ext_vector_type(16)));
typedef unsigned int u32x4 __attribute__((ext_vector_type(4)));

// ws: Kbf [8][4096][128] bf16, rows pre-swizzled (chunk16 ^= pos&7)      (8 MB)
//     Vt  [8][64 tiles][128 d][64 kv] bf16, pre-swizzled (chunk ^= d&7)  (8 MB)

__device__ __forceinline__ void gload16(const void* g, void* l) {
    __builtin_amdgcn_global_load_lds(
        (const __attribute__((address_space(1))) unsigned int*)g,
        (__attribute__((address_space(3))) unsigned int*)l, 16, 0, 0);
}

__device__ __forceinline__ unsigned int pk2(float a, float b) {
    union { __bf16 h; unsigned short u; } x, y;
    x.h = (__bf16)a; y.h = (__bf16)b;
    return (unsigned int)x.u | ((unsigned int)y.u << 16);
}

__device__ __forceinline__ float exp2fast(float x) {
    return __builtin_amdgcn_exp2f(x);   // v_exp_f32: D = 2^S0
}

__device__ __forceinline__ u32x4 nt_load(const u32x4* p) {
    return __builtin_nontemporal_load(p);
}
__device__ __forceinline__ void nt_store(u32x4* p, u32x4 v) {
    __builtin_nontemporal_store(v, p);
}

// ---------------- Kernel A: bf16 K pack + swizzled V^T pack (bp row only) ----------
__global__ __launch_bounds__(256) void pack_kernel(
    const float4* __restrict__ kn, const float4* __restrict__ vn,
    const float4* __restrict__ pk, const float4* __restrict__ pv,
    const int* __restrict__ bp_p, const int* __restrict__ sp_p,
    __bf16* __restrict__ kbf, __bf16* __restrict__ vt)
{
    __shared__ float vtile[8][132];               // padded: column reads conflict-free
    int li = blockIdx.x * 256 + threadIdx.x;     // within-batch float4 index (2^20 total)
    int bp = *bp_p, sp = *sp_p;
    int d4  = li & 31;
    int pos = (li >> 5) & 4095;
    int kvh = li >> 17;
    float4 kv4, vv4;
    if (pos >= sp && pos < sp + QL) {
        int ns = (kvh * QL + (pos - sp)) * 32 + d4;
        kv4 = kn[ns]; vv4 = vn[ns];
    } else {
        int gi = (bp << 20) + li;
        kv4 = pk[gi]; vv4 = pv[gi];
    }
    {
        bf16x4 o;
        o[0] = (__bf16)kv4.x; o[1] = (__bf16)kv4.y;
        o[2] = (__bf16)kv4.z; o[3] = (__bf16)kv4.w;
        int c16 = d4 >> 1, half = d4 & 1;
        *(bf16x4*)(kbf + ((size_t)kvh * MS + pos) * HD
                       + ((c16 ^ (pos & 7)) * 8 + half * 4)) = o;
        *(float4*)&vtile[threadIdx.x >> 5][d4 * 4] = vv4;
    }
    __syncthreads();
    if (threadIdx.x < 128) {
        int d  = threadIdx.x;
        int p0 = (blockIdx.x * 8) & 4095;        // block's first pos (multiple of 8)
        int pt = p0 >> 6, chk = (p0 & 63) >> 3;
        bf16x8 o;
        #pragma unroll
        for (int j = 0; j < 8; ++j) o[j] = (__bf16)vtile[j][d];
        *(bf16x8*)(vt + (((size_t)kvh * 64 + pt) * HD + d) * 64
                      + ((chk ^ (d & 7)) * 8)) = o;
    }
}

// ---------------- Mega kernel: role-interleaved attn(K-dbuf, V-from-L2) + copy -----
// 1024 blocks x 256 thr, 32KB LDS. role = (bid>>8)&1: CU c holds {A,C,A,C} ->
// 2 dbuf-attn blocks (8 waves, full speed) + 2 copy blocks (own vmcnt queues, no
// shared barriers). V is read per-wave from L2 (pre-swizzled ws), issued BEFORE the
// K-stage so V-use vmcnt waits never drain the prefetch (R8 lesson).
__global__ __launch_bounds__(256, 2) void mega_kernel(
    const float* __restrict__ q,
    const int* __restrict__ bp_p, const int* __restrict__ sp_p,
    const float* __restrict__ scale_p,
    const __bf16* __restrict__ kbf, const __bf16* __restrict__ vt,
    const float4* __restrict__ knf, const float4* __restrict__ vnf,
    const float4* __restrict__ pkf, const float4* __restrict__ pvf,
    float4* __restrict__ okf, float4* __restrict__ ovf,
    float* __restrict__ out)
{
    __shared__ __align__(16) unsigned char smem[32768];   // K dbuf 2x16KB; epilogue reuse

    const int bid = blockIdx.x;
    const int tid = threadIdx.x;
    const int sp  = *sp_p;
    const int bp  = *bp_p;

    if ((bid >> 8) & 1) {
        // ================= COPY ROLE: 16384 float4 of one cache ==================
        int cslot = (bid < 512) ? (bid - 256) : (bid - 768) + 256;
        const u32x4* csrc_new  = (const u32x4*)((cslot < 256) ? knf : vnf);
        const u32x4* csrc_past = (const u32x4*)((cslot < 256) ? pkf : pvf);
        u32x4*       cdst      = (u32x4*)((cslot < 256) ? okf : ovf);
        const int    cbase     = (cslot & 255) * 16384;
        for (int s = 0; s < 16; ++s) {
            u32x4 t[4];
            #pragma unroll
            for (int jj = 0; jj < 4; ++jj) {
                int idx = cbase + s * 1024 + jj * 256 + tid;
                int d4  = idx & 31;
                int pos = (idx >> 5) & 4095;
                int ck  = (idx >> 17) & 7;
                int b   = idx >> 20;
                t[jj] = (b == bp && pos >= sp && pos < sp + QL)
                    ? nt_load(&csrc_new[(ck * QL + (pos - sp)) * 32 + d4])
                    : nt_load(&csrc_past[idx]);
            }
            #pragma unroll
            for (int jj = 0; jj < 4; ++jj)
                nt_store(&cdst[cbase + s * 1024 + jj * 256 + tid], t[jj]);
        }
        return;
    }

    // ==================== ATTN ROLE (dbuf K in LDS, V direct from L2) =============
    const int attnIdx = (bid < 256) ? bid : bid - 256;    // 0..511
    const float scl = *scale_p * 1.44269504088896340736f;  // fold log2(e): exp2 domain

    // XCD-aware decode: attnIdx%8 == kvh so each XCD owns one kv-head (4MB = L2)
    int kvh = attnIdx & 7;
    int inner = (attnIdx & 255) >> 3;   // 0..31
    int headLocal = inner & 3;
    int j = inner >> 2;                 // 0..7
    int qtile = (attnIdx < 256) ? j : 15 - j;   // pair long+short
    int head = kvh * 4 + headLocal;

    const int q0     = qtile * 64;
    const int wave   = tid >> 6;
    const int qsub   = wave & 1;        // which 32 q-rows
    const int kvhalf = wave >> 1;       // which 32-kv half of each super-tile
    const int lane   = tid & 63;
    const int hi     = lane >> 5;
    const int c31    = lane & 31;
    const int qb     = q0 + qsub * 32;
    const int myq    = qb + c31;

    const unsigned char* krow = (const unsigned char*)(kbf + (size_t)kvh * MS * HD);
    const unsigned char* vrow = (const unsigned char*)(vt + (size_t)kvh * 64 * HD * 64);

    // ---- Q B-fragments (hoisted, scale*log2e folded) ----
    bf16x8 qf[8];
    #pragma unroll
    for (int dc = 0; dc < 8; ++dc) {
        const float* src = q + ((size_t)(head * QL + qb + c31) * HD + dc * 16 + hi * 8);
        float4 f0 = *(const float4*)src;
        float4 f1 = *(const float4*)(src + 4);
        bf16x8 v;
        v[0]=(__bf16)(f0.x*scl); v[1]=(__bf16)(f0.y*scl);
        v[2]=(__bf16)(f0.z*scl); v[3]=(__bf16)(f0.w*scl);
        v[4]=(__bf16)(f1.x*scl); v[5]=(__bf16)(f1.y*scl);
        v[6]=(__bf16)(f1.z*scl); v[7]=(__bf16)(f1.w*scl);
        qf[dc] = v;
    }

    f32x16 acc[4];
    #pragma unroll
    for (int dsub = 0; dsub < 4; ++dsub)
        #pragma unroll
        for (int r = 0; r < 16; ++r) acc[dsub][r] = 0.f;
    float m_run = -1e30f, l_run = 0.f;

    const int n_super = (sp + q0 + 64) >> 6;

    // stage one K tile (16KB) into LDS buffer: 4 x gload16 per thread
    auto stageK = [&](int buf, int t) {
        const unsigned char* kt = krow + (size_t)t * 16384;
        unsigned char* kl = smem + buf * 16384;
        #pragma unroll
        for (int p = 0; p < 4; ++p) {
            int off = p * 4096 + tid * 16;
            gload16(kt + off, kl + off);
        }
    };

    int cur = 0;
    stageK(0, 0);
    __syncthreads();

    for (int it = 0; it < n_super; ++it) {
        const int n0 = it * KVB + kvhalf * 32;   // this wave's 32-kv window

        // ---- V fragment loads for CURRENT tile, issued FIRST (oldest in vmcnt) ----
        u32x4 vraw[4][2];
        {
            const unsigned char* vtb = vrow + (size_t)it * 16384;
            #pragma unroll
            for (int dsub = 0; dsub < 4; ++dsub) {
                #pragma unroll
                for (int qd = 0; qd < 2; ++qd) {
                    int vr = dsub * 32 + c31;
                    int ksg = kvhalf * 2 + qd;
                    vraw[dsub][qd] = *(const u32x4*)(vtb + vr * 128
                        + (((ksg * 2 + hi) ^ (vr & 7)) << 4));
                }
            }
        }
        __builtin_amdgcn_sched_barrier(0);   // pin: V loads before K prefetch
        if (it + 1 < n_super) stageK(cur ^ 1, it + 1);

        const unsigned char* Ksm = smem + cur * 16384;

        // ---- QK^T (swapped): two independent 4-deep MFMA chains ----
        f32x16 st0, st1;
        #pragma unroll
        for (int r = 0; r < 16; ++r) { st0[r] = 0.f; st1[r] = 0.f; }
        int kr = kvhalf * 32 + c31;
        __builtin_amdgcn_s_setprio(1);
        #pragma unroll
        for (int dc = 0; dc < 4; ++dc) {
            bf16x8 ka = *(const bf16x8*)(Ksm + kr * 256 + (((2 * dc + hi) ^ (kr & 7)) << 4));
            st0 = __builtin_amdgcn_mfma_f32_32x32x16_bf16(ka, qf[dc], st0, 0, 0, 0);
            bf16x8 kb = *(const bf16x8*)(Ksm + kr * 256 + (((2 * (dc + 4) + hi) ^ (kr & 7)) << 4));
            st1 = __builtin_amdgcn_mfma_f32_32x32x16_bf16(kb, qf[dc + 4], st1, 0, 0, 0);
        }
        __builtin_amdgcn_s_setprio(0);
        f32x16 st = st0 + st1;

        // ---- mask + in-register row max (pairwise tree) ----
        const bool need_mask = (n0 + 31) > (sp + qb);
        if (need_mask) {
            #pragma unroll
            for (int r = 0; r < 16; ++r) {
                int kvg = n0 + (r & 3) + 8 * (r >> 2) + 4 * hi;
                if (kvg > sp + myq) st[r] = -1e30f;
            }
        }
        float m01 = fmaxf(fmaxf(st[0], st[1]), fmaxf(st[2], st[3]));
        float m23 = fmaxf(fmaxf(st[4], st[5]), fmaxf(st[6], st[7]));
        float m45 = fmaxf(fmaxf(st[8], st[9]), fmaxf(st[10], st[11]));
        float m67 = fmaxf(fmaxf(st[12], st[13]), fmaxf(st[14], st[15]));
        float mx = fmaxf(fmaxf(m01, m23), fmaxf(m45, m67));
        mx = fmaxf(mx, __shfl_xor(mx, 32));

        // ---- defer-max rescale (rare), exp2 domain ----
        if (!__all(mx <= m_run + 8.0f)) {
            float nm = fmaxf(m_run, mx);
            float corr = exp2fast(m_run - nm);
            m_run = nm;
            l_run *= corr;
            #pragma unroll
            for (int r = 0; r < 16; ++r) {
                int qsrc = (r & 3) + 8 * (r >> 2) + 4 * hi;
                float cq = __shfl(corr, qsrc);
                acc[0][r] *= cq; acc[1][r] *= cq; acc[2][r] *= cq; acc[3][r] *= cq;
            }
        }

        // ---- exp2 + tree sum (in-register) ----
        #pragma unroll
        for (int r = 0; r < 16; ++r) st[r] = exp2fast(st[r] - m_run);
        {
            float s0 = (st[0] + st[1]) + (st[2] + st[3]);
            float s1 = (st[4] + st[5]) + (st[6] + st[7]);
            float s2 = (st[8] + st[9]) + (st[10] + st[11]);
            float s3 = (st[12] + st[13]) + (st[14] + st[15]);
            l_run += (s0 + s1) + (s2 + s3);
        }

        // ---- pack P to bf16, permlane32_swap half-exchange, assemble PA frags ----
        unsigned int loW[4], hiW[4];
        #pragma unroll
        for (int qd = 0; qd < 2; ++qd) {
            int b = qd * 8;
            loW[qd*2+0] = pk2(st[b+0], st[b+1]);
            loW[qd*2+1] = pk2(st[b+2], st[b+3]);
            hiW[qd*2+0] = pk2(st[b+4], st[b+5]);
            hiW[qd*2+1] = pk2(st[b+6], st[b+7]);
        }
        bf16x8 pfrag[2];
        #pragma unroll
        for (int qd = 0; qd < 2; ++qd) {
            unsigned int a0 = loW[qd*2+0], b0 = hiW[qd*2+0];
            unsigned int a1 = loW[qd*2+1], b1 = hiW[qd*2+1];
            asm("v_permlane32_swap_b32 %0, %1" : "+v"(a0), "+v"(b0));
            asm("v_permlane32_swap_b32 %0, %1" : "+v"(a1), "+v"(b1));
            union { unsigned int u[4]; bf16x8 v; } fu;
            fu.u[0] = a0; fu.u[1] = a1; fu.u[2] = b0; fu.u[3] = b1;
            pfrag[qd] = fu.v;
        }

        // ---- PV: O(32q x 128d) += P(32x32) . V(32x128) from registers ----
        __builtin_amdgcn_s_setprio(1);
        #pragma unroll
        for (int dsub = 0; dsub < 4; ++dsub) {
            #pragma unroll
            for (int qd = 0; qd < 2; ++qd) {
                union { u32x4 u; bf16x8 v; } cvt;
                cvt.u = vraw[dsub][qd];
                acc[dsub] = __builtin_amdgcn_mfma_f32_32x32x16_bf16(pfrag[qd], cvt.v, acc[dsub], 0, 0, 0);
            }
        }
        __builtin_amdgcn_s_setprio(0);

        __syncthreads();   // K(t+1) staged (vmcnt0) + LDS reads of buf[cur] done
        cur ^= 1;
    }

    // ---- epilogue: merge kv-half pairs via LDS (bf16 partials), normalize, store --
    float l_full = l_run + __shfl_xor(l_run, 32);
    float* mlm = (float*)smem;            // [4][32] running max
    float* mll = (float*)smem + 128;      // [4][32] denom
    if (hi == 0) { mlm[wave * 32 + c31] = m_run; mll[wave * 32 + c31] = l_full; }
    __syncthreads();
    int pw = wave ^ 2;
    float m_o = mlm[pw * 32 + c31];
    float l_o = mll[pw * 32 + c31];
    float m_n = fmaxf(m_run, m_o);
    float sc   = exp2fast(m_run - m_n);
    float sc_o = exp2fast(m_o - m_n);
    float linv = 1.0f / (l_full * sc + l_o * sc_o);
    __bf16* Oex = (__bf16*)(smem + 1024) + (size_t)qsub * 32 * 128;   // 16KB total
    if (kvhalf) {
        #pragma unroll
        for (int r = 0; r < 16; ++r) {
            int qsrc = (r & 3) + 8 * (r >> 2) + 4 * hi;
            float s = __shfl(sc, qsrc);
            #pragma unroll
            for (int dsub = 0; dsub < 4; ++dsub)
                Oex[qsrc * 128 + dsub * 32 + c31] = (__bf16)(acc[dsub][r] * s);
        }
    }
    __syncthreads();
    if (!kvhalf) {
        #pragma unroll
        for (int r = 0; r < 16; ++r) {
            int qsrc = (r & 3) + 8 * (r >> 2) + 4 * hi;
            float s  = __shfl(sc, qsrc);
            float lq = __shfl(linv, qsrc);
            float* orow = out + (size_t)(qb + qsrc) * (NH * HD) + head * HD;
            #pragma unroll
            for (int dsub = 0; dsub < 4; ++dsub)
                orow[dsub * 32 + c31] =
                    (acc[dsub][r] * s + (float)Oex[qsrc * 128 + dsub * 32 + c31]) * lq;
        }
    }
}

// ---------------- launch ----------------
extern "C" void kernel_launch(void* const* d_in, const int* in_sizes, int n_in,
                              void* d_out, int out_size, void* d_ws, size_t ws_size,
                              hipStream_t stream)
{
    const float* q_st   = (const float*)d_in[0];
    const float* k_new  = (const float*)d_in[1];
    const float* v_new  = (const float*)d_in[2];
    const int*   bp_p   = (const int*)d_in[4];
    const float* past_k = (const float*)d_in[5];
    const float* past_v = (const float*)d_in[6];
    const int*   sp_p   = (const int*)d_in[7];
    const float* scl_p  = (const float*)d_in[8];

    float* out_attn = (float*)d_out;                       // [1024][4096]
    float* out_k    = out_attn + (size_t)QL * NH * HD;     // [4][8][4096][128]
    float* out_v    = out_k + (size_t)4 * KVHN * MS * HD;

    __bf16* kbf = (__bf16*)d_ws;                           // [8][4096][128] swizzled
    __bf16* vtw = kbf + (size_t)KVHN * MS * HD;            // [8][64][128][64] swizzled

    pack_kernel<<<4096, 256, 0, stream>>>(
        (const float4*)k_new, (const float4*)v_new,
        (const float4*)past_k, (const float4*)past_v,
        bp_p, sp_p, kbf, vtw);

    mega_kernel<<<1024, 256, 0, stream>>>(
        q_st, bp_p, sp_p, scl_p, kbf, vtw,
        (const float4*)k_new, (const float4*)v_new,
        (const float4*)past_k, (const float4*)past_v,
        (float4*)out_k, (float4*)out_v, out_attn);
}